// Round 7
// baseline (1107.307 us; speedup 1.0000x reference)
//
#include <hip/hip_runtime.h>

// VectorQuantizer: latents (16,128,64,64) f32, codebook (1024,128) f32.
// out[b,d,h,w] = codebook[argmin_k fl(fl(x2 - 2*dot(x,e_k)) + e2_k)][d]
//
// Round-7 structure (m97 pattern): B operands via double-buffered LDS
// (lesson r4-r6: global->VGPR MFMA operands get sunk by the allocator ->
// per-iter L2 stalls; lesson r2: never via SMEM path). Branch-free top-3
// per-cell tracking; per-px classification with rigorous bf16 error margin;
// exact fp32 serial-chain rescue only for ambiguous px. np first-index
// tie-break preserved (ties always flagged -> exact lex rescue).

typedef __attribute__((ext_vector_type(8))) short short8;
typedef __attribute__((ext_vector_type(4))) float f32x4;

#define VQ_D 128
#define VQ_K 1024
#define VQ_HW 4096

__device__ inline unsigned short f2bf(float f) {   // RNE fp32->bf16
    unsigned u = __float_as_uint(f);
    return (unsigned short)((u + 0x7FFFu + ((u >> 16) & 1u)) >> 16);
}

// prep: e2 (validated serial chain) + transposed bf16 codebook cbt[d8][1024][8]
__global__ __launch_bounds__(128)
void vq_prep_kernel(const float* __restrict__ cb, unsigned short* __restrict__ cbt,
                    float* __restrict__ e2) {
    const int k = blockIdx.x * 128 + threadIdx.x;
    const float* crow = cb + (size_t)k * VQ_D;
    float s = 0.f;
    #pragma unroll
    for (int d8 = 0; d8 < 16; ++d8) {
        unsigned w[4];
        #pragma unroll
        for (int jj = 0; jj < 4; ++jj) {
            const float v0 = crow[d8 * 8 + jj * 2];
            const float v1 = crow[d8 * 8 + jj * 2 + 1];
            s = fmaf(v0, v0, s);
            s = fmaf(v1, v1, s);
            w[jj] = (unsigned)f2bf(v0) | ((unsigned)f2bf(v1) << 16);
        }
        uint4 q; q.x = w[0]; q.y = w[1]; q.z = w[2]; q.w = w[3];
        *(uint4*)(cbt + ((size_t)d8 * VQ_K + k) * 8) = q;
    }
    e2[k] = s;
}

// minima top-3 merge: (a1<=a2<=a3, apk=i1|i2<<16) merged with b-triple.
__device__ inline void merge3(float& a1, float& a2, float& a3, unsigned& apk,
                              float b1, float b2, float b3, unsigned bpk) {
    const bool aw = (a1 <= b1);
    const float w1 = aw ? a1 : b1, w2 = aw ? a2 : b2, w3 = aw ? a3 : b3;
    const float l1 = aw ? b1 : a1, l2 = aw ? b2 : a2;
    const unsigned wpk = aw ? apk : bpk, lpk = aw ? bpk : apk;
    const bool t2 = (w2 <= l1);
    const float c2 = t2 ? w2 : l1;
    const float c3 = t2 ? fminf(w3, l1) : fminf(w2, l2);
    const unsigned i2 = t2 ? (wpk >> 16) : (lpk & 0xFFFFu);
    a1 = w1; a2 = c2; a3 = c3;
    apk = (wpk & 0xFFFFu) | (i2 << 16);
}

__global__ __launch_bounds__(256, 4)
void vq_main_kernel(const float* __restrict__ latents,
                    const float* __restrict__ cb,
                    const unsigned short* __restrict__ cbt,
                    const float* __restrict__ e2g,
                    float* __restrict__ out) {
    __shared__ __align__(16) unsigned short Bbuf[2][16 * 64 * 8];  // 2 x 16 KB
    __shared__ float e2l[VQ_K];                                    // 4 KB
    __shared__ float x2s[64];

    // post-loop overlay into Bbuf (dead after last chunk barrier)
    char* ov = (char*)&Bbuf[0][0];
    unsigned long long* fkey = (unsigned long long*)ov;            // 64*8 = 512
    float* hC1 = (float*)(ov + 512);                               // 2*64*4
    float* hC2 = (float*)(ov + 1024);
    float* hC3 = (float*)(ov + 1536);
    unsigned* hPk = (unsigned*)(ov + 2048);                        // 2*64*4
    unsigned* c2jobs = (unsigned*)(ov + 2560);                     // 160*4
    int* fulljobs = (int*)(ov + 3200);                             // 64*4
    int* nctr = (int*)(ov + 3456);                                 // n2, nfull

    const int tid  = threadIdx.x;
    const int lane = tid & 63;
    const int wave = __builtin_amdgcn_readfirstlane(tid >> 6);
    const int quad = lane >> 4, mm = lane & 15;
    const int blk  = blockIdx.x;
    const int b    = blk >> 6;
    const int hw0  = (blk & 63) << 6;
    const int pxb  = (wave >> 1) << 5;   // px half base 0/32
    const int h    = wave & 1;           // code half

    const float* xg = latents + (size_t)b * VQ_D * VQ_HW + hw0;

    // stage e2 -> LDS
    *(float4*)(e2l + tid * 4) = *(const float4*)(e2g + tid * 4);

    // A-frags direct from global (one-time, L1/L2-hot): px=pxb+p*16+mm,
    // d = t*32 + quad*8 + j
    short8 A[2][4];
    #pragma unroll
    for (int p = 0; p < 2; ++p) {
        #pragma unroll
        for (int t = 0; t < 4; ++t) {
            const float* src = xg + (size_t)(t * 32 + quad * 8) * VQ_HW + pxb + p * 16 + mm;
            short8 a;
            #pragma unroll
            for (int j = 0; j < 8; ++j) a[j] = (short)f2bf(src[(size_t)j * VQ_HW]);
            A[p][t] = a;
        }
    }

    // x2 per px: exact serial ascending-d chain (validated numerics)
    if (tid < 64) {
        float s = 0.f;
        #pragma unroll
        for (int d = 0; d < VQ_D; ++d) {
            const float v = xg[(size_t)d * VQ_HW + tid];
            s = fmaf(v, v, s);
        }
        x2s[tid] = s;
    }

    // staging: thread covers slot=tid&63 (codes), d8 = wave*4 + r
    const int scode = ((tid & 32) ? 512 : 0) + (tid & 31);
    int4 st[4];
    auto stageLoad = [&](int ck) {
        #pragma unroll
        for (int r = 0; r < 4; ++r) {
            const int d8 = wave * 4 + r;
            st[r] = *(const int4*)(cbt + ((size_t)d8 * VQ_K + scode + ck * 32) * 8);
        }
    };
    auto stageWrite = [&](int bufi) {
        #pragma unroll
        for (int r = 0; r < 4; ++r) {
            const int d8 = wave * 4 + r;
            *(int4*)(&Bbuf[bufi][((d8 * 64) + (tid & 63)) * 8]) = st[r];
        }
    };

    stageLoad(0);
    stageWrite(0);

    // per-cell top-3 minima state; cell = p*4+r -> px = pxb+p*16+quad*4+r,
    // code dim = lane mm
    float M1[8], M2[8], M3[8];
    unsigned PK[8];
    #pragma unroll
    for (int i = 0; i < 8; ++i) { M1[i] = 3e38f; M2[i] = 3e38f; M3[i] = 3e38f; PK[i] = 0; }

    __syncthreads();   // Bbuf[0], e2l ready

    #pragma unroll 1
    for (int ck = 0; ck < 16; ++ck) {
        if (ck < 15) stageLoad(ck + 1);
        const unsigned short* bp = &Bbuf[ck & 1][0];

        #pragma unroll
        for (int cg = 0; cg < 2; ++cg) {
            const int cbase = h * 512 + ck * 32 + cg * 16;
            const float e2c = e2l[cbase + mm];
            short8 B[4];
            #pragma unroll
            for (int t = 0; t < 4; ++t)
                B[t] = *(const short8*)(bp + ((t * 4 + quad) * 64 + h * 32 + cg * 16 + mm) * 8);
            f32x4 C[2] = {{0.f,0.f,0.f,0.f},{0.f,0.f,0.f,0.f}};
            #pragma unroll
            for (int t = 0; t < 4; ++t) {
                C[0] = __builtin_amdgcn_mfma_f32_16x16x32_bf16(A[0][t], B[t], C[0], 0, 0, 0);
                C[1] = __builtin_amdgcn_mfma_f32_16x16x32_bf16(A[1][t], B[t], C[1], 0, 0, 0);
            }
            const unsigned code = (unsigned)(cbase + mm);
            #pragma unroll
            for (int p = 0; p < 2; ++p) {
                #pragma unroll
                for (int r = 0; r < 4; ++r) {
                    const int cl = p * 4 + r;
                    const float s = fmaf(-2.0f, C[p][r], e2c);
                    const bool b1 = s < M1[cl];
                    const bool b2 = s < M2[cl];
                    const bool b3 = s < M3[cl];
                    M3[cl] = b2 ? M2[cl] : (b3 ? s : M3[cl]);
                    M2[cl] = b1 ? M1[cl] : (b2 ? s : M2[cl]);
                    PK[cl] = b1 ? (code | (PK[cl] << 16))
                                : (b2 ? ((PK[cl] & 0xFFFFu) | (code << 16)) : PK[cl]);
                    M1[cl] = b1 ? s : M1[cl];
                }
            }
        }
        if (ck < 15) stageWrite((ck + 1) & 1);
        __syncthreads();
    }

    // reduce over the 16 mm-lanes (code dimension)
    #pragma unroll
    for (int stp = 1; stp < 16; stp <<= 1) {
        #pragma unroll
        for (int cl = 0; cl < 8; ++cl) {
            const float b1 = __shfl_xor(M1[cl], stp);
            const float b2 = __shfl_xor(M2[cl], stp);
            const float b3 = __shfl_xor(M3[cl], stp);
            const unsigned bp2 = (unsigned)__shfl_xor((int)PK[cl], stp);
            merge3(M1[cl], M2[cl], M3[cl], PK[cl], b1, b2, b3, bp2);
        }
    }

    // overlay phase: write per-(half,px) triples; init counters/fkey
    if (mm == 0) {
        #pragma unroll
        for (int p = 0; p < 2; ++p) {
            #pragma unroll
            for (int r = 0; r < 4; ++r) {
                const int cl = p * 4 + r;
                const int px = pxb + p * 16 + quad * 4 + r;
                hC1[h * 64 + px] = M1[cl];
                hC2[h * 64 + px] = M2[cl];
                hC3[h * 64 + px] = M3[cl];
                hPk[h * 64 + px] = PK[cl];
            }
        }
    }
    if (tid == 0) { nctr[0] = 0; nctr[1] = 0; }
    if (tid < 64) fkey[tid] = ~0ULL;
    __syncthreads();

    // classify per px (tid<64): safe / 2-cand / full
    if (tid < 64) {
        float m1 = hC1[tid], m2 = hC2[tid], m3 = hC3[tid];
        unsigned pk = hPk[tid];
        merge3(m1, m2, m3, pk, hC1[64 + tid], hC2[64 + tid], hC3[64 + tid], hPk[64 + tid]);
        // rigorous margin: |s_bf - (t3-x2)| <= 2^-7*1.002*||x||*Emax + 3.5e-5,
        // Emax < sqrt(128)/1024 (input spec) -> coef 8.7e-5
        const float w = 2.0f * (8.7e-5f * sqrtf(x2s[tid]) + 3.5e-5f);
        if (m2 - m1 > w) {
            fkey[tid] = (unsigned long long)(pk & 0xFFFFu);   // winner = i1
        } else if (m3 - m1 > w) {
            const int j = atomicAdd(&nctr[0], 2);
            c2jobs[j]     = (unsigned)tid | ((pk & 0xFFFFu) << 16);
            c2jobs[j + 1] = (unsigned)tid | ((pk >> 16) << 16);
        } else {
            fulljobs[atomicAdd(&nctr[1], 1)] = tid;
        }
    }
    __syncthreads();

    // exact fp32 serial ascending-d chain (validated rounds 1-6)
    auto exact_t3 = [&](int px, int k) -> float {
        const float* crow = cb + (size_t)k * VQ_D;
        float dot = 0.f;
        #pragma unroll
        for (int q = 0; q < 32; ++q) {
            const float4 cv = *(const float4*)(crow + q * 4);
            dot = fmaf(xg[(size_t)(4 * q + 0) * VQ_HW + px], cv.x, dot);
            dot = fmaf(xg[(size_t)(4 * q + 1) * VQ_HW + px], cv.y, dot);
            dot = fmaf(xg[(size_t)(4 * q + 2) * VQ_HW + px], cv.z, dot);
            dot = fmaf(xg[(size_t)(4 * q + 3) * VQ_HW + px], cv.w, dot);
        }
        return (x2s[px] - 2.0f * dot) + e2l[k];
    };

    // 2-candidate rescue: lex (t3,k) atomicMin keeps np first-index ties
    const int n2 = nctr[0];
    if (tid < n2) {
        const unsigned job = c2jobs[tid];
        const int px = (int)(job & 0xFFFFu);
        const int k  = (int)(job >> 16);
        const float t3 = exact_t3(px, k);
        atomicMin(&fkey[px], ((unsigned long long)__float_as_uint(t3) << 32) | (unsigned)k);
    }
    // full-scan rescue (rare)
    const int nfull = nctr[1];
    for (int f = 0; f < nfull; ++f) {
        const int px = fulljobs[f];
        for (int k = tid; k < VQ_K; k += 256) {
            const float t3 = exact_t3(px, k);
            atomicMin(&fkey[px], ((unsigned long long)__float_as_uint(t3) << 32) | (unsigned)k);
        }
    }
    __syncthreads();

    // writeback: px = tid&63, d-range (tid>>6)*32..+32
    {
        const int px = tid & 63;
        const int dh = tid >> 6;
        const int fb = (int)(fkey[px] & 0xFFFFu);
        const float* crow = cb + (size_t)fb * VQ_D;
        float* og = out + (size_t)b * VQ_D * VQ_HW + hw0;
        #pragma unroll
        for (int i = 0; i < 32; ++i) {
            const int d = dh * 32 + i;
            og[(size_t)d * VQ_HW + px] = crow[d];
        }
    }
}

extern "C" void kernel_launch(void* const* d_in, const int* in_sizes, int n_in,
                              void* d_out, int out_size, void* d_ws, size_t ws_size,
                              hipStream_t stream) {
    const float* latents = (const float*)d_in[0];
    const float* cb      = (const float*)d_in[1];
    unsigned short* cbt  = (unsigned short*)d_ws;              // 256 KB transposed bf16
    float* e2            = (float*)((char*)d_ws + 262144);     // 4 KB
    float* out           = (float*)d_out;

    vq_prep_kernel<<<dim3(8), dim3(128), 0, stream>>>(cb, cbt, e2);
    vq_main_kernel<<<dim3(1024), dim3(256), 0, stream>>>(latents, cb, cbt, e2, out);
}

// Round 8
// 649.196 us; speedup vs baseline: 1.7057x; 1.7057x over previous
//
#include <hip/hip_runtime.h>

// VectorQuantizer: latents (16,128,64,64) f32, codebook (1024,128) f32.
// out[b,d,h,w] = codebook[argmin_k fl(fl(x2 - 2*dot(x,e_k)) + e2_k)][d]
//
// Round-8: minimal-register MFMA design.
//  - wave = 16 px x 1024 codes: A frags = 16 VGPRs only.
//  - B staged to double-buffered LDS via global_load_lds width=16 (zero
//    staging regs; lesson r4-r7: any global->VGPR MFMA operand path or big
//    per-lane state gets spilled/sunk by the allocator).
//  - per-lane sorted top-4 of packed scores: u32 = (bits(s'+0.5) & ~1023)|code
//    (s' = e2 - 2*dot_bf in (-0.5,0.5) -> positive float, monotone unsigned;
//    low 10 bits = code -> exact first-index tie order).
//  - classify per px with rigorous margin w: gap>w -> winner certain;
//    top-3 cover -> 3 exact rescores; else full exact 1024-scan (rare).
//    Exact path = serial ascending-d fp32 fmaf chain (validated r1-r7),
//    lex (t3,k) u64 atomicMin -> np first-index ties.

typedef __attribute__((ext_vector_type(8))) short short8;
typedef __attribute__((ext_vector_type(4))) float f32x4;

#define VQ_D 128
#define VQ_K 1024
#define VQ_HW 4096

__device__ inline unsigned short f2bf(float f) {   // RNE fp32->bf16
    unsigned u = __float_as_uint(f);
    return (unsigned short)((u + 0x7FFFu + ((u >> 16) & 1u)) >> 16);
}
__device__ inline unsigned umn(unsigned a, unsigned b) { return a < b ? a : b; }
__device__ inline unsigned umx(unsigned a, unsigned b) { return a > b ? a : b; }

// prep: e2 (validated serial chain) + transposed bf16 codebook cbt[d8][1024][8]
__global__ __launch_bounds__(128)
void vq_prep_kernel(const float* __restrict__ cb, unsigned short* __restrict__ cbt,
                    float* __restrict__ e2) {
    const int k = blockIdx.x * 128 + threadIdx.x;
    const float* crow = cb + (size_t)k * VQ_D;
    float s = 0.f;
    #pragma unroll
    for (int d8 = 0; d8 < 16; ++d8) {
        unsigned w[4];
        #pragma unroll
        for (int jj = 0; jj < 4; ++jj) {
            const float v0 = crow[d8 * 8 + jj * 2];
            const float v1 = crow[d8 * 8 + jj * 2 + 1];
            s = fmaf(v0, v0, s);
            s = fmaf(v1, v1, s);
            w[jj] = (unsigned)f2bf(v0) | ((unsigned)f2bf(v1) << 16);
        }
        uint4 q; q.x = w[0]; q.y = w[1]; q.z = w[2]; q.w = w[3];
        *(uint4*)(cbt + ((size_t)d8 * VQ_K + k) * 8) = q;
    }
    e2[k] = s;
}

__global__ __launch_bounds__(256, 2)
void vq_main_kernel(const float* __restrict__ latents,
                    const float* __restrict__ cb,
                    const unsigned short* __restrict__ cbt,
                    const float* __restrict__ e2g,
                    float* __restrict__ out) {
    __shared__ __align__(16) unsigned short Bbuf[2][16 * 64 * 8];  // 32 KB
    __shared__ float e2l[VQ_K];                                    // 4 KB
    __shared__ float x2s[64];

    // overlay into Bbuf after the main loop's final barrier
    char* ov = (char*)&Bbuf[0][0];
    unsigned* s1 = (unsigned*)ov;                       // [64]
    unsigned* s2 = (unsigned*)(ov + 256);
    unsigned* s3 = (unsigned*)(ov + 512);
    unsigned* s4 = (unsigned*)(ov + 768);
    unsigned long long* fkey = (unsigned long long*)(ov + 1024);   // [64]
    unsigned* jobs3 = (unsigned*)(ov + 1536);           // [192]
    int* fpx  = (int*)(ov + 2304);                      // [64]
    int* nctr = (int*)(ov + 2560);                      // n3, nf

    const int tid  = threadIdx.x;
    const int lane = tid & 63;
    const int wave = __builtin_amdgcn_readfirstlane(tid >> 6);
    const int quad = lane >> 4, mm = lane & 15;
    const int blk  = blockIdx.x;
    const int b    = blk >> 6;
    const int hw0  = (blk & 63) << 6;
    const int pxg  = wave << 4;          // wave's 16-px group

    const float* xg = latents + (size_t)b * VQ_D * VQ_HW + hw0;

    // stage e2 -> LDS (covered by the first in-loop barrier)
    *(float4*)(e2l + tid * 4) = *(const float4*)(e2g + tid * 4);

    // A frags (16 VGPRs): px = pxg + mm, d = t*32 + quad*8 + j
    short8 A[4];
    #pragma unroll
    for (int t = 0; t < 4; ++t) {
        const float* src = xg + (size_t)(t * 32 + quad * 8) * VQ_HW + pxg + mm;
        short8 a;
        #pragma unroll
        for (int j = 0; j < 8; ++j) a[j] = (short)f2bf(src[(size_t)j * VQ_HW]);
        A[t] = a;
    }

    // x2 per px: exact serial ascending-d chain (validated numerics)
    float x2 = 0.f;
    if (tid < 64) {
        #pragma unroll
        for (int d = 0; d < VQ_D; ++d) {
            const float v = xg[(size_t)d * VQ_HW + tid];
            x2 = fmaf(v, v, x2);
        }
        x2s[tid] = x2;
    }

    // async staging: wave handles d8 = wave*4+r; lane i -> code slot i (16 B)
    auto stage = [&](int ck, int buf) {
        #pragma unroll
        for (int r = 0; r < 4; ++r) {
            const int d8 = wave * 4 + r;
            const unsigned short* g = cbt + ((size_t)d8 * VQ_K + ck * 64 + lane) * 8;
            unsigned short* l = &Bbuf[buf][(d8 * 64) * 8];
            __builtin_amdgcn_global_load_lds(
                (const __attribute__((address_space(1))) unsigned*)g,
                (__attribute__((address_space(3))) unsigned*)l, 16, 0, 0);
        }
    };
    stage(0, 0);

    // per-lane sorted top-4 packed minima, cells r=0..3 -> px = pxg+quad*4+r
    unsigned m1[4], m2[4], m3[4], m4[4];
    #pragma unroll
    for (int r = 0; r < 4; ++r) { m1[r] = ~0u; m2[r] = ~0u; m3[r] = ~0u; m4[r] = ~0u; }

    #pragma unroll 1
    for (int ck = 0; ck < 16; ++ck) {
        __syncthreads();   // chunk ck landed; buf[(ck+1)&1] readers done
        if (ck < 15) stage(ck + 1, (ck + 1) & 1);
        const unsigned short* bp = &Bbuf[ck & 1][0];

        #pragma unroll 1
        for (int cg = 0; cg < 4; ++cg) {
            short8 B[4];
            #pragma unroll
            for (int t = 0; t < 4; ++t)
                B[t] = *(const short8*)(bp + ((t * 4 + quad) * 64 + cg * 16 + mm) * 8);
            f32x4 C = {0.f, 0.f, 0.f, 0.f};
            #pragma unroll
            for (int t = 0; t < 4; ++t)
                C = __builtin_amdgcn_mfma_f32_16x16x32_bf16(A[t], B[t], C, 0, 0, 0);
            const int code = ck * 64 + cg * 16 + mm;
            const float e2c5 = e2l[code] + 0.5f;
            #pragma unroll
            for (int r = 0; r < 4; ++r) {
                const float s5 = fmaf(-2.0f, C[r], e2c5);   // s' + 0.5, positive
                const unsigned u = (__float_as_uint(s5) & 0xFFFFFC00u) | (unsigned)code;
                m4[r] = umn(m4[r], umx(m3[r], u));          // old m3
                m3[r] = umn(m3[r], umx(m2[r], u));          // old m2
                m2[r] = umn(m2[r], umx(m1[r], u));          // old m1
                m1[r] = umn(m1[r], u);
            }
        }
    }
    __syncthreads();   // Bbuf dead -> overlay writable

    // reduce sorted-4 across the 16 mm-lanes (code dimension)
    #pragma unroll
    for (int st = 1; st < 16; st <<= 1) {
        #pragma unroll
        for (int r = 0; r < 4; ++r) {
            const unsigned a1 = m1[r], a2 = m2[r], a3 = m3[r], a4 = m4[r];
            const unsigned b1 = (unsigned)__shfl_xor((int)a1, st);
            const unsigned b2 = (unsigned)__shfl_xor((int)a2, st);
            const unsigned b3 = (unsigned)__shfl_xor((int)a3, st);
            const unsigned b4 = (unsigned)__shfl_xor((int)a4, st);
            const unsigned l1 = umn(a1, b1), h1 = umx(a1, b1);
            const unsigned l2 = umn(a2, b2), h2 = umx(a2, b2);
            const unsigned l3 = umn(a3, b3), l4 = umn(a4, b4);
            m1[r] = l1;
            m2[r] = umn(h1, l2);
            const unsigned t = umx(h1, l2);
            m3[r] = umn(t, l3);
            m4[r] = umn(umx(t, l3), umn(h2, l4));
        }
    }
    if (mm == 0) {
        #pragma unroll
        for (int r = 0; r < 4; ++r) {
            const int px = pxg + quad * 4 + r;
            s1[px] = m1[r]; s2[px] = m2[r]; s3[px] = m3[r]; s4[px] = m4[r];
        }
    }
    if (tid == 0) { nctr[0] = 0; nctr[1] = 0; }
    __syncthreads();

    // classify per px. Rigor: |s'(k) - (t3(k)-x2+0.5)| <= werr =
    // 8.7e-5*sqrt(x2)+3.5e-5 (bf16 Cauchy-Schwarz, ||e||<=sqrt(128)/1024,
    // + fl roundings); packed truncation <= 6.1e-5. w covers 2*werr + trunc.
    if (tid < 64) {
        const unsigned u1 = s1[tid], u2 = s2[tid], u3 = s3[tid], u4 = s4[tid];
        const float v1 = __uint_as_float(u1 & 0xFFFFFC00u);
        const float v2 = __uint_as_float(u2 & 0xFFFFFC00u);
        const float v4 = __uint_as_float(u4 & 0xFFFFFC00u);
        const float w  = 2.0f * (8.7e-5f * sqrtf(x2) + 3.5e-5f) + 1.3e-4f;
        if (v2 - v1 > w) {
            fkey[tid] = (unsigned long long)(u1 & 1023u);   // winner certain
        } else {
            fkey[tid] = ~0ULL;
            if (v4 - v1 > w) {   // true argmin provably within top-3
                const int j = atomicAdd(&nctr[0], 3);
                jobs3[j]     = (unsigned)tid | ((u1 & 1023u) << 16);
                jobs3[j + 1] = (unsigned)tid | ((u2 & 1023u) << 16);
                jobs3[j + 2] = (unsigned)tid | ((u3 & 1023u) << 16);
            } else {
                fpx[atomicAdd(&nctr[1], 1)] = tid;          // full exact scan
            }
        }
    }
    __syncthreads();

    // exact fp32 serial ascending-d chain (validated r1-r7)
    auto exact_t3 = [&](int px, int k) -> float {
        const float* crow = cb + (size_t)k * VQ_D;
        float dot = 0.f;
        #pragma unroll
        for (int q = 0; q < 32; ++q) {
            const float4 cv = *(const float4*)(crow + q * 4);
            dot = fmaf(xg[(size_t)(4 * q + 0) * VQ_HW + px], cv.x, dot);
            dot = fmaf(xg[(size_t)(4 * q + 1) * VQ_HW + px], cv.y, dot);
            dot = fmaf(xg[(size_t)(4 * q + 2) * VQ_HW + px], cv.z, dot);
            dot = fmaf(xg[(size_t)(4 * q + 3) * VQ_HW + px], cv.w, dot);
        }
        return (x2s[px] - 2.0f * dot) + e2l[k];
    };

    // 3-candidate rescue (n3 <= 192 < 256: one pass)
    const int n3 = nctr[0];
    if (tid < n3) {
        const unsigned jb = jobs3[tid];
        const int px = (int)(jb & 0xFFFFu);
        const int k  = (int)(jb >> 16);
        const float t3 = exact_t3(px, k);
        atomicMin(&fkey[px], ((unsigned long long)__float_as_uint(t3) << 32) | (unsigned)k);
    }
    // full-scan rescue (rare)
    const int nf = nctr[1];
    for (int f = 0; f < nf; ++f) {
        const int px = fpx[f];
        for (int k = tid; k < VQ_K; k += 256) {
            const float t3 = exact_t3(px, k);
            atomicMin(&fkey[px], ((unsigned long long)__float_as_uint(t3) << 32) | (unsigned)k);
        }
    }
    __syncthreads();

    // writeback: px = tid&63, d-range (tid>>6)*32..+32
    {
        const int px = tid & 63;
        const int dh = tid >> 6;
        const int fb = (int)(fkey[px] & 1023u);
        const float* crow = cb + (size_t)fb * VQ_D;
        float* og = out + (size_t)b * VQ_D * VQ_HW + hw0;
        #pragma unroll
        for (int i = 0; i < 32; ++i) {
            const int d = dh * 32 + i;
            og[(size_t)d * VQ_HW + px] = crow[d];
        }
    }
}

extern "C" void kernel_launch(void* const* d_in, const int* in_sizes, int n_in,
                              void* d_out, int out_size, void* d_ws, size_t ws_size,
                              hipStream_t stream) {
    const float* latents = (const float*)d_in[0];
    const float* cb      = (const float*)d_in[1];
    unsigned short* cbt  = (unsigned short*)d_ws;              // 256 KB transposed bf16
    float* e2            = (float*)((char*)d_ws + 262144);     // 4 KB
    float* out           = (float*)d_out;

    vq_prep_kernel<<<dim3(8), dim3(128), 0, stream>>>(cb, cbt, e2);
    vq_main_kernel<<<dim3(1024), dim3(256), 0, stream>>>(latents, cb, cbt, e2, out);
}